// Round 1
// baseline (305.996 us; speedup 1.0000x reference)
//
#include <hip/hip_runtime.h>
#include <math.h>

#define NN 10000      // nodes
#define NE 160000     // edges
#define C  32         // FEAT == EMB == HID == 32
#define ED 9          // edge feature dim

// ---------------------------------------------------------------------------
// u_kernel: U[n, k*32+o] = sum_i xin[n,i] * wb[k, i*32+o]
//           xb[n, o]     = sum_i xin[n,i] * bb[i*32+o]
// one block per node, 256 threads, each thread does 4 (k,o) pairs.
// ---------------------------------------------------------------------------
__global__ __launch_bounds__(256) void u_kernel(const float* __restrict__ xin,
                                                const float* __restrict__ wb,
                                                const float* __restrict__ bb,
                                                float* __restrict__ U,
                                                float* __restrict__ xb) {
    __shared__ float xs[C];
    const int n   = blockIdx.x;
    const int tid = threadIdx.x;
    if (tid < C) xs[tid] = xin[n * C + tid];
    __syncthreads();
#pragma unroll
    for (int t = 0; t < 4; ++t) {
        const int idx = t * 256 + tid;       // 0..1023  (k = idx>>5, o = idx&31)
        const int k = idx >> 5, o = idx & 31;
        float acc = 0.f;
#pragma unroll
        for (int i = 0; i < C; ++i) acc += xs[i] * wb[k * (C * C) + i * C + o];
        U[(size_t)n * (C * C) + idx] = acc;
    }
    if (tid < C) {
        float acc = 0.f;
#pragma unroll
        for (int i = 0; i < C; ++i) acc += xs[i] * bb[i * C + tid];
        xb[n * C + tid] = acc;
    }
}

// ---------------------------------------------------------------------------
// edge_kernel: per edge e: h = relu(ea[e]@wa + ba)  (32)
//              msg[o] = xb[src,o] + sum_k h[k]*U[src, k*32+o]
//              atomicAdd(sum[dst,o], msg[o]); count edges per dst (conv1 only)
// 256 threads = 8 edges x 32 lanes.
// ---------------------------------------------------------------------------
template <int COUNT>
__global__ __launch_bounds__(256) void edge_kernel(const int* __restrict__ ei,
                                                   const float* __restrict__ ea,
                                                   const float* __restrict__ wa,
                                                   const float* __restrict__ ba,
                                                   const float* __restrict__ U,
                                                   const float* __restrict__ xb,
                                                   float* __restrict__ sumbuf,
                                                   int* __restrict__ cnt) {
    __shared__ float was[ED * C];
    __shared__ float bas[C];
    __shared__ float hs[8][C];
    const int tid = threadIdx.x;
    for (int t = tid; t < ED * C; t += 256) was[t] = wa[t];
    if (tid < C) bas[tid] = ba[tid];
    const int el = tid >> 5;   // edge slot 0..7
    const int o  = tid & 31;   // channel / hid lane
    const int e  = blockIdx.x * 8 + el;
    __syncthreads();
    if (e < NE) {
        float hacc = bas[o];
#pragma unroll
        for (int j = 0; j < ED; ++j) hacc += ea[e * ED + j] * was[j * C + o];
        hs[el][o] = fmaxf(hacc, 0.f);
    }
    __syncthreads();
    if (e < NE) {
        const int src = ei[e];
        const int dst = ei[NE + e];
        const float* Up = U + (size_t)src * (C * C) + o;
        float acc = xb[src * C + o];
#pragma unroll
        for (int k = 0; k < C; ++k) acc += hs[el][k] * Up[k * C];
        atomicAdd(&sumbuf[dst * C + o], acc);
        if (COUNT && o == 0) atomicAdd(&cnt[dst], 1);
    }
}

// ---------------------------------------------------------------------------
// node_kernel: out[n,o] = relu(sum[n,o]/max(cnt,1) + sum_i xin[n,i]*root[i,o] + bias[o])
// 256 threads = 8 nodes x 32 lanes.
// ---------------------------------------------------------------------------
__global__ __launch_bounds__(256) void node_kernel(const float* __restrict__ xin,
                                                   const float* __restrict__ sumbuf,
                                                   const int* __restrict__ cnt,
                                                   const float* __restrict__ root,
                                                   const float* __restrict__ bias,
                                                   float* __restrict__ outb) {
    __shared__ float rs[C * C];
    __shared__ float bs[C];
    __shared__ float xs[8][C];
    const int tid = threadIdx.x;
    for (int t = tid; t < C * C; t += 256) rs[t] = root[t];
    if (tid < C) bs[tid] = bias[tid];
    const int nl = tid >> 5, o = tid & 31;
    const int n  = blockIdx.x * 8 + nl;
    xs[nl][o] = (n < NN) ? xin[n * C + o] : 0.f;
    __syncthreads();
    if (n < NN) {
        float acc = bs[o];
#pragma unroll
        for (int i = 0; i < C; ++i) acc += xs[nl][i] * rs[i * C + o];
        const float cn = fmaxf((float)cnt[n], 1.f);
        acc += sumbuf[n * C + o] / cn;
        outb[n * C + o] = fmaxf(acc, 0.f);
    }
}

// ---------------------------------------------------------------------------
// score_kernel: scores[n] = sum_o h[n,o] * emb[signal, o]
// ---------------------------------------------------------------------------
__global__ __launch_bounds__(256) void score_kernel(const float* __restrict__ h,
                                                    const float* __restrict__ emb,
                                                    const int* __restrict__ signal,
                                                    float* __restrict__ scores) {
    __shared__ float sig[C];
    if (threadIdx.x < C) sig[threadIdx.x] = emb[(size_t)signal[0] * C + threadIdx.x];
    __syncthreads();
    const int n = blockIdx.x * 256 + threadIdx.x;
    if (n < NN) {
        float acc = 0.f;
#pragma unroll
        for (int o = 0; o < C; ++o) acc += h[n * C + o] * sig[o];
        scores[n] = acc;
    }
}

// ---------------------------------------------------------------------------
// reduce_kernel: single block; red[0] = max(scores), red[1] = log(sum exp(s-max))
// ---------------------------------------------------------------------------
__global__ __launch_bounds__(1024) void reduce_kernel(const float* __restrict__ scores,
                                                      float* __restrict__ red) {
    __shared__ float sm[16];
    __shared__ float ss[16];
    const int tid = threadIdx.x;
    float m = -INFINITY;
    for (int n = tid; n < NN; n += 1024) m = fmaxf(m, scores[n]);
    for (int off = 32; off; off >>= 1) m = fmaxf(m, __shfl_down(m, off, 64));
    if ((tid & 63) == 0) sm[tid >> 6] = m;
    __syncthreads();
    if (tid == 0) {
        float mm = sm[0];
        for (int w = 1; w < 16; ++w) mm = fmaxf(mm, sm[w]);
        sm[0] = mm;
    }
    __syncthreads();
    const float gmax = sm[0];
    float s = 0.f;
    for (int n = tid; n < NN; n += 1024) s += expf(scores[n] - gmax);
    for (int off = 32; off; off >>= 1) s += __shfl_down(s, off, 64);
    if ((tid & 63) == 0) ss[tid >> 6] = s;
    __syncthreads();
    if (tid == 0) {
        float t = 0.f;
        for (int w = 0; w < 16; ++w) t += ss[w];
        red[0] = gmax;
        red[1] = logf(t);
    }
}

__global__ __launch_bounds__(256) void out_kernel(const float* __restrict__ scores,
                                                  const float* __restrict__ red,
                                                  float* __restrict__ out) {
    const int n = blockIdx.x * 256 + threadIdx.x;
    if (n < NN) out[n] = scores[n] - red[0] - red[1];
}

// ---------------------------------------------------------------------------
extern "C" void kernel_launch(void* const* d_in, const int* in_sizes, int n_in,
                              void* d_out, int out_size, void* d_ws, size_t ws_size,
                              hipStream_t stream) {
    const int*   signal = (const int*)d_in[0];
    const float* x      = (const float*)d_in[1];
    const int*   ei     = (const int*)d_in[2];
    const float* ea     = (const float*)d_in[3];
    const float* w1a    = (const float*)d_in[4];
    const float* b1a    = (const float*)d_in[5];
    const float* w1b    = (const float*)d_in[6];
    const float* b1b    = (const float*)d_in[7];
    const float* root1  = (const float*)d_in[8];
    const float* bias1  = (const float*)d_in[9];
    const float* w2a    = (const float*)d_in[10];
    const float* b2a    = (const float*)d_in[11];
    const float* w2b    = (const float*)d_in[12];
    const float* b2b    = (const float*)d_in[13];
    const float* root2  = (const float*)d_in[14];
    const float* bias2  = (const float*)d_in[15];
    const float* emb    = (const float*)d_in[16];

    float* ws     = (float*)d_ws;
    float* U      = ws;                       // 10,240,000 floats (41 MB)
    float* xb     = U + (size_t)NN * C * C;   // 320,000
    float* sumbuf = xb + NN * C;              // 320,000
    float* h1     = sumbuf + NN * C;          // 320,000
    float* h2     = h1 + NN * C;              // 320,000
    float* scores = h2 + NN * C;              // 10,000
    float* red    = scores + NN;              // 8
    int*   cnt    = (int*)(red + 8);          // 10,000 ints

    hipMemsetAsync(sumbuf, 0, NN * C * sizeof(float), stream);
    hipMemsetAsync(cnt, 0, NN * sizeof(int), stream);

    // ---- conv1 ----
    u_kernel<<<NN, 256, 0, stream>>>(x, w1b, b1b, U, xb);
    edge_kernel<1><<<NE / 8, 256, 0, stream>>>(ei, ea, w1a, b1a, U, xb, sumbuf, cnt);
    node_kernel<<<NN / 8, 256, 0, stream>>>(x, sumbuf, cnt, root1, bias1, h1);

    // ---- conv2 ----
    hipMemsetAsync(sumbuf, 0, NN * C * sizeof(float), stream);
    u_kernel<<<NN, 256, 0, stream>>>(h1, w2b, b2b, U, xb);
    edge_kernel<0><<<NE / 8, 256, 0, stream>>>(ei, ea, w2a, b2a, U, xb, sumbuf, cnt);
    node_kernel<<<NN / 8, 256, 0, stream>>>(h1, sumbuf, cnt, root2, bias2, h2);

    // ---- readout ----
    score_kernel<<<(NN + 255) / 256, 256, 0, stream>>>(h2, emb, signal, scores);
    reduce_kernel<<<1, 1024, 0, stream>>>(scores, red);
    out_kernel<<<(NN + 255) / 256, 256, 0, stream>>>(scores, red, (float*)d_out);
}

// Round 2
// 276.857 us; speedup vs baseline: 1.1052x; 1.1052x over previous
//
#include <hip/hip_runtime.h>
#include <math.h>

#define NN 10000      // nodes
#define NE 160000     // edges
#define C  32         // FEAT == EMB == HID == 32
#define ED 9          // edge feature dim

__device__ inline unsigned short f2bf(float f) {        // fp32 -> bf16 RNE
    unsigned int u = __float_as_uint(f);
    unsigned int r = (u + 0x7fffu + ((u >> 16) & 1u)) >> 16;
    return (unsigned short)r;
}
__device__ inline float bf2f(unsigned int us) { return __uint_as_float(us << 16); }

// ---------------------------------------------------------------------------
// hist_kernel: out-degree histogram (src) for CSR + in-degree (dst) for mean
// ---------------------------------------------------------------------------
__global__ __launch_bounds__(256) void hist_kernel(const int* __restrict__ ei,
                                                   int* __restrict__ cnt_src,
                                                   int* __restrict__ cnt_dst) {
    const int e = blockIdx.x * 256 + threadIdx.x;
    if (e < NE) {
        atomicAdd(&cnt_src[ei[e]], 1);
        atomicAdd(&cnt_dst[ei[NE + e]], 1);
    }
}

// ---------------------------------------------------------------------------
// scan_kernel: exclusive prefix sum of cnt_src[10000] -> offs[10001]
// single block, 1024 threads, 10 elements/thread + Hillis-Steele on partials
// ---------------------------------------------------------------------------
__global__ __launch_bounds__(1024) void scan_kernel(const int* __restrict__ cnt,
                                                    int* __restrict__ offs) {
    __shared__ int part[1024];
    const int t = threadIdx.x;
    const int base = t * 10;
    int loc[10];
    int s = 0;
#pragma unroll
    for (int j = 0; j < 10; ++j) {
        int v = (base + j < NN) ? cnt[base + j] : 0;
        loc[j] = s;
        s += v;
    }
    part[t] = s;
    __syncthreads();
    for (int off = 1; off < 1024; off <<= 1) {
        int v = (t >= off) ? part[t - off] : 0;
        __syncthreads();
        part[t] += v;
        __syncthreads();
    }
    const int excl = (t == 0) ? 0 : part[t - 1];
#pragma unroll
    for (int j = 0; j < 10; ++j)
        if (base + j < NN) offs[base + j] = excl + loc[j];
    if (t == 1023) offs[NN] = part[1023];
}

// ---------------------------------------------------------------------------
// scatter_kernel: build CSR payload: dst_s[pos], ea_s[pos*9..] sorted by src
// ---------------------------------------------------------------------------
__global__ __launch_bounds__(256) void scatter_kernel(const int* __restrict__ ei,
                                                      const float* __restrict__ ea,
                                                      const int* __restrict__ offs,
                                                      int* __restrict__ cursor,
                                                      int* __restrict__ dst_s,
                                                      float* __restrict__ ea_s) {
    const int e = blockIdx.x * 256 + threadIdx.x;
    if (e < NE) {
        const int b   = ei[e];
        const int pos = offs[b] + atomicAdd(&cursor[b], 1);
        dst_s[pos] = ei[NE + e];
#pragma unroll
        for (int j = 0; j < ED; ++j)
            ea_s[(size_t)pos * ED + j] = ea[(size_t)e * ED + j];
    }
}

// ---------------------------------------------------------------------------
// u_kernel: U[n, k*32+o] = sum_i xin[n,i] * wb[k, i*32+o]   (stored bf16)
//           xb[n, o]     = sum_i xin[n,i] * bb[i*32+o]      (fp32)
// ---------------------------------------------------------------------------
__global__ __launch_bounds__(256) void u_kernel(const float* __restrict__ xin,
                                                const float* __restrict__ wb,
                                                const float* __restrict__ bb,
                                                unsigned short* __restrict__ U,
                                                float* __restrict__ xb) {
    __shared__ float xs[C];
    const int n   = blockIdx.x;
    const int tid = threadIdx.x;
    if (tid < C) xs[tid] = xin[n * C + tid];
    __syncthreads();
#pragma unroll
    for (int t = 0; t < 4; ++t) {
        const int idx = t * 256 + tid;       // 0..1023  (k = idx>>5, o = idx&31)
        const int k = idx >> 5, o = idx & 31;
        float acc = 0.f;
#pragma unroll
        for (int i = 0; i < C; ++i) acc += xs[i] * wb[k * (C * C) + i * C + o];
        U[(size_t)n * (C * C) + idx] = f2bf(acc);
    }
    if (tid < C) {
        float acc = 0.f;
#pragma unroll
        for (int i = 0; i < C; ++i) acc += xs[i] * bb[i * C + tid];
        xb[n * C + tid] = acc;
    }
}

// ---------------------------------------------------------------------------
// edge2_kernel: one wave per src node. Stage U[src] (bf16->fp32) in LDS once,
// then loop over the src's out-edges 2 at a time (half-wave each):
//   h = relu(ea_s[p]@wa + ba); msg[o] = xb[src,o] + sum_k h[k]*U[src,k,o]
//   atomicAdd(sumbuf[dst,o], msg[o])
// grid = NN/4 blocks x 4 waves, so s < NN always.
// ---------------------------------------------------------------------------
__global__ __launch_bounds__(256) void edge2_kernel(const int* __restrict__ offs,
                                                    const int* __restrict__ dst_s,
                                                    const float* __restrict__ ea_s,
                                                    const float* __restrict__ wa,
                                                    const float* __restrict__ ba,
                                                    const unsigned short* __restrict__ U,
                                                    const float* __restrict__ xb,
                                                    float* __restrict__ sumbuf) {
    __shared__ float Us[4][C * C];
    __shared__ float was[ED * C];
    __shared__ float bas[C];
    const int tid = threadIdx.x;
    for (int t = tid; t < ED * C; t += 256) was[t] = wa[t];
    if (tid < C) bas[tid] = ba[tid];
    __syncthreads();

    const int w    = tid >> 6;
    const int lane = tid & 63;
    const int el   = lane >> 5;   // edge slot within wave
    const int o    = lane & 31;   // output channel
    const int s    = blockIdx.x * 4 + w;

    // stage U[s] into LDS as fp32 (wave-local; no block barrier needed)
    const unsigned short* Ug = U + (size_t)s * (C * C);
#pragma unroll
    for (int t = 0; t < 4; ++t) {
        const int idx = (t * 64 + lane) * 4;                 // 4 elems / lane / iter
        const uint2 v = *reinterpret_cast<const uint2*>(Ug + idx);
        Us[w][idx + 0] = bf2f(v.x & 0xffffu);
        Us[w][idx + 1] = bf2f(v.x >> 16);
        Us[w][idx + 2] = bf2f(v.y & 0xffffu);
        Us[w][idx + 3] = bf2f(v.y >> 16);
    }

    const float xbv = xb[s * C + o];
    const int e0 = offs[s], e1 = offs[s + 1];
    for (int p = e0 + el; p < e1; p += 2) {
        float hacc = bas[o];
#pragma unroll
        for (int j = 0; j < ED; ++j) hacc += ea_s[(size_t)p * ED + j] * was[j * C + o];
        const float h = fmaxf(hacc, 0.f);
        float acc = xbv;
#pragma unroll
        for (int k = 0; k < C; ++k) {
            const float hk = __shfl(h, el * 32 + k, 64);     // within own half-wave
            acc += hk * Us[w][k * C + o];
        }
        atomicAdd(&sumbuf[(size_t)dst_s[p] * C + o], acc);
    }
}

// ---------------------------------------------------------------------------
// node_kernel: out[n,o] = relu(sum[n,o]/max(cnt,1) + sum_i xin[n,i]*root[i,o] + bias[o])
// ---------------------------------------------------------------------------
__global__ __launch_bounds__(256) void node_kernel(const float* __restrict__ xin,
                                                   const float* __restrict__ sumbuf,
                                                   const int* __restrict__ cnt,
                                                   const float* __restrict__ root,
                                                   const float* __restrict__ bias,
                                                   float* __restrict__ outb) {
    __shared__ float rs[C * C];
    __shared__ float bs[C];
    __shared__ float xs[8][C];
    const int tid = threadIdx.x;
    for (int t = tid; t < C * C; t += 256) rs[t] = root[t];
    if (tid < C) bs[tid] = bias[tid];
    const int nl = tid >> 5, o = tid & 31;
    const int n  = blockIdx.x * 8 + nl;
    xs[nl][o] = (n < NN) ? xin[n * C + o] : 0.f;
    __syncthreads();
    if (n < NN) {
        float acc = bs[o];
#pragma unroll
        for (int i = 0; i < C; ++i) acc += xs[nl][i] * rs[i * C + o];
        const float cn = fmaxf((float)cnt[n], 1.f);
        acc += sumbuf[n * C + o] / cn;
        outb[n * C + o] = fmaxf(acc, 0.f);
    }
}

// ---------------------------------------------------------------------------
__global__ __launch_bounds__(256) void score_kernel(const float* __restrict__ h,
                                                    const float* __restrict__ emb,
                                                    const int* __restrict__ signal,
                                                    float* __restrict__ scores) {
    __shared__ float sig[C];
    if (threadIdx.x < C) sig[threadIdx.x] = emb[(size_t)signal[0] * C + threadIdx.x];
    __syncthreads();
    const int n = blockIdx.x * 256 + threadIdx.x;
    if (n < NN) {
        float acc = 0.f;
#pragma unroll
        for (int o = 0; o < C; ++o) acc += h[n * C + o] * sig[o];
        scores[n] = acc;
    }
}

__global__ __launch_bounds__(1024) void reduce_kernel(const float* __restrict__ scores,
                                                      float* __restrict__ red) {
    __shared__ float sm[16];
    __shared__ float ss[16];
    const int tid = threadIdx.x;
    float m = -INFINITY;
    for (int n = tid; n < NN; n += 1024) m = fmaxf(m, scores[n]);
    for (int off = 32; off; off >>= 1) m = fmaxf(m, __shfl_down(m, off, 64));
    if ((tid & 63) == 0) sm[tid >> 6] = m;
    __syncthreads();
    if (tid == 0) {
        float mm = sm[0];
        for (int w = 1; w < 16; ++w) mm = fmaxf(mm, sm[w]);
        sm[0] = mm;
    }
    __syncthreads();
    const float gmax = sm[0];
    float s = 0.f;
    for (int n = tid; n < NN; n += 1024) s += expf(scores[n] - gmax);
    for (int off = 32; off; off >>= 1) s += __shfl_down(s, off, 64);
    if ((tid & 63) == 0) ss[tid >> 6] = s;
    __syncthreads();
    if (tid == 0) {
        float t = 0.f;
        for (int w = 0; w < 16; ++w) t += ss[w];
        red[0] = gmax;
        red[1] = logf(t);
    }
}

__global__ __launch_bounds__(256) void out_kernel(const float* __restrict__ scores,
                                                  const float* __restrict__ red,
                                                  float* __restrict__ out) {
    const int n = blockIdx.x * 256 + threadIdx.x;
    if (n < NN) out[n] = scores[n] - red[0] - red[1];
}

// ---------------------------------------------------------------------------
extern "C" void kernel_launch(void* const* d_in, const int* in_sizes, int n_in,
                              void* d_out, int out_size, void* d_ws, size_t ws_size,
                              hipStream_t stream) {
    const int*   signal = (const int*)d_in[0];
    const float* x      = (const float*)d_in[1];
    const int*   ei     = (const int*)d_in[2];
    const float* ea     = (const float*)d_in[3];
    const float* w1a    = (const float*)d_in[4];
    const float* b1a    = (const float*)d_in[5];
    const float* w1b    = (const float*)d_in[6];
    const float* b1b    = (const float*)d_in[7];
    const float* root1  = (const float*)d_in[8];
    const float* bias1  = (const float*)d_in[9];
    const float* w2a    = (const float*)d_in[10];
    const float* b2a    = (const float*)d_in[11];
    const float* w2b    = (const float*)d_in[12];
    const float* b2b    = (const float*)d_in[13];
    const float* root2  = (const float*)d_in[14];
    const float* bias2  = (const float*)d_in[15];
    const float* emb    = (const float*)d_in[16];

    // ---- workspace layout (float-equivalent slots) ----
    float* ws = (float*)d_ws;
    unsigned short* U = (unsigned short*)ws;          // 10,240,000 bf16 (20.5 MB)
    float* xb     = ws + 5120000;                     // 320,000
    float* sumbuf = xb + NN * C;                      // 320,000
    float* h1     = sumbuf + NN * C;                  // 320,000
    float* h2     = h1 + NN * C;                      // 320,000
    float* ea_s   = h2 + NN * C;                      // 1,440,000
    float* scores = ea_s + (size_t)NE * ED;           // 10,000
    float* red    = scores + NN;                      // 16
    int*   cnt_src = (int*)(red + 16);                // 10,000 \  zeroed in
    int*   cnt_dst = cnt_src + NN;                    // 10,000  | one memset
    int*   cursor  = cnt_dst + NN;                    // 10,000 /
    int*   offs    = cursor + NN;                     // 10,016
    int*   dst_s   = offs + NN + 16;                  // 160,000

    hipMemsetAsync(cnt_src, 0, 3 * NN * sizeof(int), stream);
    hipMemsetAsync(sumbuf, 0, NN * C * sizeof(float), stream);

    // ---- CSR by src (reused by both convs) ----
    hist_kernel<<<(NE + 255) / 256, 256, 0, stream>>>(ei, cnt_src, cnt_dst);
    scan_kernel<<<1, 1024, 0, stream>>>(cnt_src, offs);
    scatter_kernel<<<(NE + 255) / 256, 256, 0, stream>>>(ei, ea, offs, cursor, dst_s, ea_s);

    // ---- conv1 ----
    u_kernel<<<NN, 256, 0, stream>>>(x, w1b, b1b, U, xb);
    edge2_kernel<<<NN / 4, 256, 0, stream>>>(offs, dst_s, ea_s, w1a, b1a, U, xb, sumbuf);
    node_kernel<<<NN / 8, 256, 0, stream>>>(x, sumbuf, cnt_dst, root1, bias1, h1);

    // ---- conv2 ----
    hipMemsetAsync(sumbuf, 0, NN * C * sizeof(float), stream);
    u_kernel<<<NN, 256, 0, stream>>>(h1, w2b, b2b, U, xb);
    edge2_kernel<<<NN / 4, 256, 0, stream>>>(offs, dst_s, ea_s, w2a, b2a, U, xb, sumbuf);
    node_kernel<<<NN / 8, 256, 0, stream>>>(h1, sumbuf, cnt_dst, root2, bias2, h2);

    // ---- readout ----
    score_kernel<<<(NN + 255) / 256, 256, 0, stream>>>(h2, emb, signal, scores);
    reduce_kernel<<<1, 1024, 0, stream>>>(scores, red);
    out_kernel<<<(NN + 255) / 256, 256, 0, stream>>>(scores, red, (float*)d_out);
}

// Round 3
// 255.641 us; speedup vs baseline: 1.1970x; 1.0830x over previous
//
#include <hip/hip_runtime.h>
#include <math.h>

#define NN 10000      // nodes
#define NE 160000     // edges
#define C  32         // FEAT == EMB == HID == 32
#define ED 9          // edge feature dim

__device__ inline unsigned short f2bf(float f) {        // fp32 -> bf16 RNE
    unsigned int u = __float_as_uint(f);
    unsigned int r = (u + 0x7fffu + ((u >> 16) & 1u)) >> 16;
    return (unsigned short)r;
}
__device__ inline float bf2f(unsigned int us) { return __uint_as_float(us << 16); }

// ---------------------------------------------------------------------------
// hist_kernel: out-degree histogram (src) for CSR + in-degree (dst) for mean
// ---------------------------------------------------------------------------
__global__ __launch_bounds__(256) void hist_kernel(const int* __restrict__ ei,
                                                   int* __restrict__ cnt_src,
                                                   int* __restrict__ cnt_dst) {
    const int e = blockIdx.x * 256 + threadIdx.x;
    if (e < NE) {
        atomicAdd(&cnt_src[ei[e]], 1);
        atomicAdd(&cnt_dst[ei[NE + e]], 1);
    }
}

// ---------------------------------------------------------------------------
// scan_kernel: exclusive prefix sum of cnt_src[10000] -> offs[10001]
// ---------------------------------------------------------------------------
__global__ __launch_bounds__(1024) void scan_kernel(const int* __restrict__ cnt,
                                                    int* __restrict__ offs) {
    __shared__ int part[1024];
    const int t = threadIdx.x;
    const int base = t * 10;
    int loc[10];
    int s = 0;
#pragma unroll
    for (int j = 0; j < 10; ++j) {
        int v = (base + j < NN) ? cnt[base + j] : 0;
        loc[j] = s;
        s += v;
    }
    part[t] = s;
    __syncthreads();
    for (int off = 1; off < 1024; off <<= 1) {
        int v = (t >= off) ? part[t - off] : 0;
        __syncthreads();
        part[t] += v;
        __syncthreads();
    }
    const int excl = (t == 0) ? 0 : part[t - 1];
#pragma unroll
    for (int j = 0; j < 10; ++j)
        if (base + j < NN) offs[base + j] = excl + loc[j];
    if (t == 1023) offs[NN] = part[1023];
}

// ---------------------------------------------------------------------------
// scatter_kernel: build CSR payload sorted by src
// ---------------------------------------------------------------------------
__global__ __launch_bounds__(256) void scatter_kernel(const int* __restrict__ ei,
                                                      const float* __restrict__ ea,
                                                      const int* __restrict__ offs,
                                                      int* __restrict__ cursor,
                                                      int* __restrict__ dst_s,
                                                      float* __restrict__ ea_s) {
    const int e = blockIdx.x * 256 + threadIdx.x;
    if (e < NE) {
        const int b   = ei[e];
        const int pos = offs[b] + atomicAdd(&cursor[b], 1);
        dst_s[pos] = ei[NE + e];
#pragma unroll
        for (int j = 0; j < ED; ++j)
            ea_s[(size_t)pos * ED + j] = ea[(size_t)e * ED + j];
    }
}

// ---------------------------------------------------------------------------
// u_gemm: U[n, k*32+o] = sum_i xin[n,i] * wb[k, i*32+o]   (bf16 out)
//         xb[n, o]     = sum_i xin[n,i] * bb[i*32+o]      (fp32)
// 625 blocks x 16 nodes. Thread owns column j=(k,o); wb column hoisted to
// 32 VGPRs (coalesced loads); x tile read as broadcast float4 from LDS.
// ---------------------------------------------------------------------------
__global__ __launch_bounds__(256) void u_gemm(const float* __restrict__ xin,
                                              const float* __restrict__ wb,
                                              const float* __restrict__ bb,
                                              unsigned short* __restrict__ U,
                                              float* __restrict__ xb) {
    __shared__ float xs[16 * C];
    const int tid = threadIdx.x;
    const int nb  = blockIdx.x * 16;          // 625*16 == 10000 exactly
    for (int t = tid; t < 16 * C; t += 256) xs[t] = xin[nb * C + t];
    __syncthreads();

    for (int pass = 0; pass < 4; ++pass) {
        const int j = pass * 256 + tid;       // column 0..1023
        const int k = j >> 5, o = j & 31;
        float wbv[C];
#pragma unroll
        for (int i = 0; i < C; ++i) wbv[i] = wb[k * (C * C) + i * C + o];
#pragma unroll
        for (int n = 0; n < 16; ++n) {
            float acc = 0.f;
#pragma unroll
            for (int i4 = 0; i4 < 8; ++i4) {
                const float4 xv = *reinterpret_cast<const float4*>(&xs[n * C + i4 * 4]);
                acc += xv.x * wbv[i4 * 4 + 0] + xv.y * wbv[i4 * 4 + 1]
                     + xv.z * wbv[i4 * 4 + 2] + xv.w * wbv[i4 * 4 + 3];
            }
            U[(size_t)(nb + n) * (C * C) + j] = f2bf(acc);
        }
    }
    // xb tile: 512 outputs, 2 per thread
#pragma unroll
    for (int t = 0; t < 2; ++t) {
        const int idx = t * 256 + tid;
        const int n = idx >> 5, o = idx & 31;
        float acc = 0.f;
#pragma unroll
        for (int i = 0; i < C; ++i) acc += xs[n * C + i] * bb[i * C + o];
        xb[(nb + n) * C + o] = acc;
    }
}

// ---------------------------------------------------------------------------
// edge3_kernel: one wave per src. 8 edges x 8 lanes; lane owns o-quad.
//   - Us[k*32+o] staged once per src (bf16->fp32)
//   - h (32) per edge computed quad-wise, staged in pad-36 LDS rows
//   - k-loop: float4 LDS reads (conflict-free / broadcast), 128 FMA/lane
//   - acc transposed through pad-33 LDS so atomics stay row-coalesced
// ---------------------------------------------------------------------------
__global__ __launch_bounds__(256) void edge3_kernel(const int* __restrict__ offs,
                                                    const int* __restrict__ dst_s,
                                                    const float* __restrict__ ea_s,
                                                    const float* __restrict__ wa,
                                                    const float* __restrict__ ba,
                                                    const unsigned short* __restrict__ U,
                                                    const float* __restrict__ xb,
                                                    float* __restrict__ sumbuf) {
    __shared__ float Us[4][C * C];
    __shared__ float hs2[4][8 * 36];
    __shared__ float accT[4][8 * 33];
    __shared__ float was[ED * C];
    __shared__ float bas[C];
    const int tid = threadIdx.x;
    for (int t = tid; t < ED * C; t += 256) was[t] = wa[t];
    if (tid < C) bas[tid] = ba[tid];
    __syncthreads();

    const int w    = tid >> 6;
    const int lane = tid & 63;
    const int s    = blockIdx.x * 4 + w;      // 2500*4 == 10000
    const int el   = lane >> 3;               // edge slot 0..7
    const int o4   = lane & 7;                // o-quad 0..7

    // stage U[s] into LDS fp32 (wave-local, in-order DS => no barrier)
    const unsigned short* Ug = U + (size_t)s * (C * C);
#pragma unroll
    for (int t = 0; t < 4; ++t) {
        const int idx = (t * 64 + lane) * 4;
        const uint2 v = *reinterpret_cast<const uint2*>(Ug + idx);
        Us[w][idx + 0] = bf2f(v.x & 0xffffu);
        Us[w][idx + 1] = bf2f(v.x >> 16);
        Us[w][idx + 2] = bf2f(v.y & 0xffffu);
        Us[w][idx + 3] = bf2f(v.y >> 16);
    }

    const float4 xb4 = *reinterpret_cast<const float4*>(&xb[s * C + o4 * 4]);
    const int e0 = offs[s], e1 = offs[s + 1];

    for (int pb = e0; pb < e1; pb += 8) {
        const int p     = pb + el;
        const bool vld  = (p < e1);
        const int  pc   = vld ? p : e0;       // clamp for safe loads
        // ---- h for edge el, hid-quad o4 ----
        {
            float h0 = bas[o4 * 4 + 0], h1 = bas[o4 * 4 + 1];
            float h2 = bas[o4 * 4 + 2], h3 = bas[o4 * 4 + 3];
#pragma unroll
            for (int j = 0; j < ED; ++j) {
                const float eav = ea_s[(size_t)pc * ED + j];
                h0 += eav * was[j * C + o4 * 4 + 0];
                h1 += eav * was[j * C + o4 * 4 + 1];
                h2 += eav * was[j * C + o4 * 4 + 2];
                h3 += eav * was[j * C + o4 * 4 + 3];
            }
            hs2[w][el * 36 + o4 * 4 + 0] = fmaxf(h0, 0.f);
            hs2[w][el * 36 + o4 * 4 + 1] = fmaxf(h1, 0.f);
            hs2[w][el * 36 + o4 * 4 + 2] = fmaxf(h2, 0.f);
            hs2[w][el * 36 + o4 * 4 + 3] = fmaxf(h3, 0.f);
        }
        // ---- msg quad: acc = xb4 + sum_k h[k] * Us[k][o4*4..+3] ----
        float4 acc = xb4;
#pragma unroll
        for (int k4 = 0; k4 < 8; ++k4) {
            const float4 hv = *reinterpret_cast<const float4*>(&hs2[w][el * 36 + k4 * 4]);
#pragma unroll
            for (int jj = 0; jj < 4; ++jj) {
                const int k = k4 * 4 + jj;
                const float4 uv = *reinterpret_cast<const float4*>(&Us[w][k * C + o4 * 4]);
                const float hj = (jj == 0) ? hv.x : (jj == 1) ? hv.y : (jj == 2) ? hv.z : hv.w;
                acc.x += hj * uv.x; acc.y += hj * uv.y;
                acc.z += hj * uv.z; acc.w += hj * uv.w;
            }
        }
        // ---- transpose through LDS, then row-coalesced atomics ----
        accT[w][el * 33 + o4 * 4 + 0] = acc.x;
        accT[w][el * 33 + o4 * 4 + 1] = acc.y;
        accT[w][el * 33 + o4 * 4 + 2] = acc.z;
        accT[w][el * 33 + o4 * 4 + 3] = acc.w;
#pragma unroll
        for (int r = 0; r < 4; ++r) {
            const int e  = r * 2 + (lane >> 5);
            const int o  = lane & 31;
            const int pe = pb + e;
            if (pe < e1)
                atomicAdd(&sumbuf[(size_t)dst_s[pe] * C + o], accT[w][e * 33 + o]);
        }
    }
}

// ---------------------------------------------------------------------------
// node_kernel: out[n,o] = relu(sum[n,o]/max(cnt,1) + sum_i xin[n,i]*root[i,o] + bias[o])
// ---------------------------------------------------------------------------
__global__ __launch_bounds__(256) void node_kernel(const float* __restrict__ xin,
                                                   const float* __restrict__ sumbuf,
                                                   const int* __restrict__ cnt,
                                                   const float* __restrict__ root,
                                                   const float* __restrict__ bias,
                                                   float* __restrict__ outb) {
    __shared__ float rs[C * C];
    __shared__ float bs[C];
    __shared__ float xs[8][C];
    const int tid = threadIdx.x;
    for (int t = tid; t < C * C; t += 256) rs[t] = root[t];
    if (tid < C) bs[tid] = bias[tid];
    const int nl = tid >> 5, o = tid & 31;
    const int n  = blockIdx.x * 8 + nl;
    xs[nl][o] = (n < NN) ? xin[n * C + o] : 0.f;
    __syncthreads();
    if (n < NN) {
        float acc = bs[o];
#pragma unroll
        for (int i = 0; i < C; ++i) acc += xs[nl][i] * rs[i * C + o];
        const float cn = fmaxf((float)cnt[n], 1.f);
        acc += sumbuf[n * C + o] / cn;
        outb[n * C + o] = fmaxf(acc, 0.f);
    }
}

// ---------------------------------------------------------------------------
__global__ __launch_bounds__(256) void score_kernel(const float* __restrict__ h,
                                                    const float* __restrict__ emb,
                                                    const int* __restrict__ signal,
                                                    float* __restrict__ scores) {
    __shared__ float sig[C];
    if (threadIdx.x < C) sig[threadIdx.x] = emb[(size_t)signal[0] * C + threadIdx.x];
    __syncthreads();
    const int n = blockIdx.x * 256 + threadIdx.x;
    if (n < NN) {
        float acc = 0.f;
#pragma unroll
        for (int o = 0; o < C; ++o) acc += h[n * C + o] * sig[o];
        scores[n] = acc;
    }
}

__global__ __launch_bounds__(1024) void reduce_kernel(const float* __restrict__ scores,
                                                      float* __restrict__ red) {
    __shared__ float sm[16];
    __shared__ float ss[16];
    const int tid = threadIdx.x;
    float m = -INFINITY;
    for (int n = tid; n < NN; n += 1024) m = fmaxf(m, scores[n]);
    for (int off = 32; off; off >>= 1) m = fmaxf(m, __shfl_down(m, off, 64));
    if ((tid & 63) == 0) sm[tid >> 6] = m;
    __syncthreads();
    if (tid == 0) {
        float mm = sm[0];
        for (int w = 1; w < 16; ++w) mm = fmaxf(mm, sm[w]);
        sm[0] = mm;
    }
    __syncthreads();
    const float gmax = sm[0];
    float s = 0.f;
    for (int n = tid; n < NN; n += 1024) s += expf(scores[n] - gmax);
    for (int off = 32; off; off >>= 1) s += __shfl_down(s, off, 64);
    if ((tid & 63) == 0) ss[tid >> 6] = s;
    __syncthreads();
    if (tid == 0) {
        float t = 0.f;
        for (int w = 0; w < 16; ++w) t += ss[w];
        red[0] = gmax;
        red[1] = logf(t);
    }
}

__global__ __launch_bounds__(256) void out_kernel(const float* __restrict__ scores,
                                                  const float* __restrict__ red,
                                                  float* __restrict__ out) {
    const int n = blockIdx.x * 256 + threadIdx.x;
    if (n < NN) out[n] = scores[n] - red[0] - red[1];
}

// ---------------------------------------------------------------------------
extern "C" void kernel_launch(void* const* d_in, const int* in_sizes, int n_in,
                              void* d_out, int out_size, void* d_ws, size_t ws_size,
                              hipStream_t stream) {
    const int*   signal = (const int*)d_in[0];
    const float* x      = (const float*)d_in[1];
    const int*   ei     = (const int*)d_in[2];
    const float* ea     = (const float*)d_in[3];
    const float* w1a    = (const float*)d_in[4];
    const float* b1a    = (const float*)d_in[5];
    const float* w1b    = (const float*)d_in[6];
    const float* b1b    = (const float*)d_in[7];
    const float* root1  = (const float*)d_in[8];
    const float* bias1  = (const float*)d_in[9];
    const float* w2a    = (const float*)d_in[10];
    const float* b2a    = (const float*)d_in[11];
    const float* w2b    = (const float*)d_in[12];
    const float* b2b    = (const float*)d_in[13];
    const float* root2  = (const float*)d_in[14];
    const float* bias2  = (const float*)d_in[15];
    const float* emb    = (const float*)d_in[16];

    // ---- workspace layout ----
    float* ws = (float*)d_ws;
    unsigned short* U = (unsigned short*)ws;          // 10,240,000 bf16 (20.5 MB)
    float* xb     = ws + 5120000;                     // 320,000
    float* sumbuf = xb + NN * C;                      // 320,000
    float* h1     = sumbuf + NN * C;                  // 320,000
    float* h2     = h1 + NN * C;                      // 320,000
    float* ea_s   = h2 + NN * C;                      // 1,440,000
    float* scores = ea_s + (size_t)NE * ED;           // 10,000
    float* red    = scores + NN;                      // 16
    int*   cnt_src = (int*)(red + 16);                // 10,000 \  zeroed in
    int*   cnt_dst = cnt_src + NN;                    // 10,000  | one memset
    int*   cursor  = cnt_dst + NN;                    // 10,000 /
    int*   offs    = cursor + NN;                     // 10,016
    int*   dst_s   = offs + NN + 16;                  // 160,000

    hipMemsetAsync(cnt_src, 0, 3 * NN * sizeof(int), stream);
    hipMemsetAsync(sumbuf, 0, NN * C * sizeof(float), stream);

    // ---- CSR by src (reused by both convs) ----
    hist_kernel<<<(NE + 255) / 256, 256, 0, stream>>>(ei, cnt_src, cnt_dst);
    scan_kernel<<<1, 1024, 0, stream>>>(cnt_src, offs);
    scatter_kernel<<<(NE + 255) / 256, 256, 0, stream>>>(ei, ea, offs, cursor, dst_s, ea_s);

    // ---- conv1 ----
    u_gemm<<<NN / 16, 256, 0, stream>>>(x, w1b, b1b, U, xb);
    edge3_kernel<<<NN / 4, 256, 0, stream>>>(offs, dst_s, ea_s, w1a, b1a, U, xb, sumbuf);
    node_kernel<<<NN / 8, 256, 0, stream>>>(x, sumbuf, cnt_dst, root1, bias1, h1);

    // ---- conv2 ----
    hipMemsetAsync(sumbuf, 0, NN * C * sizeof(float), stream);
    u_gemm<<<NN / 16, 256, 0, stream>>>(h1, w2b, b2b, U, xb);
    edge3_kernel<<<NN / 4, 256, 0, stream>>>(offs, dst_s, ea_s, w2a, b2a, U, xb, sumbuf);
    node_kernel<<<NN / 8, 256, 0, stream>>>(h1, sumbuf, cnt_dst, root2, bias2, h2);

    // ---- readout ----
    score_kernel<<<(NN + 255) / 256, 256, 0, stream>>>(h2, emb, signal, scores);
    reduce_kernel<<<1, 1024, 0, stream>>>(scores, red);
    out_kernel<<<(NN + 255) / 256, 256, 0, stream>>>(scores, red, (float*)d_out);
}

// Round 4
// 182.914 us; speedup vs baseline: 1.6729x; 1.3976x over previous
//
#include <hip/hip_runtime.h>
#include <math.h>

#define NN 10000      // nodes
#define NE 160000     // edges
#define C  32         // FEAT == EMB == HID == 32
#define ED 9          // edge feature dim
#define EAP 12        // padded edge-attr stride (16B-aligned float4 loads)

typedef __attribute__((ext_vector_type(8))) short short8v;   // 8 bf16 (4 VGPR)
typedef __attribute__((ext_vector_type(4))) float float4v;

__device__ inline unsigned short f2bf(float f) {        // fp32 -> bf16 RNE
    unsigned int u = __float_as_uint(f);
    return (unsigned short)((u + 0x7fffu + ((u >> 16) & 1u)) >> 16);
}

// ---------------------------------------------------------------------------
// hist_kernel: out-degree histogram (src) for CSR + in-degree (dst) for mean
// ---------------------------------------------------------------------------
__global__ __launch_bounds__(256) void hist_kernel(const int* __restrict__ ei,
                                                   int* __restrict__ cnt_src,
                                                   int* __restrict__ cnt_dst) {
    const int e = blockIdx.x * 256 + threadIdx.x;
    if (e < NE) {
        atomicAdd(&cnt_src[ei[e]], 1);
        atomicAdd(&cnt_dst[ei[NE + e]], 1);
    }
}

// ---------------------------------------------------------------------------
// scan_kernel: exclusive prefix sum of cnt_src[10000] -> offs[10001]
// ---------------------------------------------------------------------------
__global__ __launch_bounds__(1024) void scan_kernel(const int* __restrict__ cnt,
                                                    int* __restrict__ offs) {
    __shared__ int part[1024];
    const int t = threadIdx.x;
    const int base = t * 10;
    int loc[10];
    int s = 0;
#pragma unroll
    for (int j = 0; j < 10; ++j) {
        int v = (base + j < NN) ? cnt[base + j] : 0;
        loc[j] = s;
        s += v;
    }
    part[t] = s;
    __syncthreads();
    for (int off = 1; off < 1024; off <<= 1) {
        int v = (t >= off) ? part[t - off] : 0;
        __syncthreads();
        part[t] += v;
        __syncthreads();
    }
    const int excl = (t == 0) ? 0 : part[t - 1];
#pragma unroll
    for (int j = 0; j < 10; ++j)
        if (base + j < NN) offs[base + j] = excl + loc[j];
    if (t == 1023) offs[NN] = part[1023];
}

// ---------------------------------------------------------------------------
// scatter_kernel: build CSR payload sorted by src (ea padded to stride 12)
// ---------------------------------------------------------------------------
__global__ __launch_bounds__(256) void scatter_kernel(const int* __restrict__ ei,
                                                      const float* __restrict__ ea,
                                                      const int* __restrict__ offs,
                                                      int* __restrict__ cursor,
                                                      int* __restrict__ dst_s,
                                                      float* __restrict__ ea_s) {
    const int e = blockIdx.x * 256 + threadIdx.x;
    if (e < NE) {
        const int b   = ei[e];
        const int pos = offs[b] + atomicAdd(&cursor[b], 1);
        dst_s[pos] = ei[NE + e];
#pragma unroll
        for (int j = 0; j < ED; ++j)
            ea_s[(size_t)pos * EAP + j] = ea[(size_t)e * ED + j];
    }
}

// ---------------------------------------------------------------------------
// wbt_kernel: wbT[o*1024 + k*32 + i] = wb[k*1024 + i*32 + o]  (32768 elems)
// gives each u_gemm2 thread a contiguous 128B wb column.
// ---------------------------------------------------------------------------
__global__ __launch_bounds__(256) void wbt_kernel(const float* __restrict__ wb,
                                                  float* __restrict__ wbT) {
    const int idx = blockIdx.x * 256 + threadIdx.x;   // 0..32767
    const int i = idx & 31, k = (idx >> 5) & 31, o = idx >> 10;
    wbT[idx] = wb[k * (C * C) + i * C + o];
}

// ---------------------------------------------------------------------------
// u_gemm2: U_T[n][o][k] = f2bf(sum_i xin[n,i] * wb[k, i*32+o])
//          xb[n][o]     = sum_i xin[n,i] * bb[i*32+o]
// 2500 blocks: (nb = 16 nodes) x (o0 = 8-of-32 o columns). Thread owns (o,k);
// wbT column hoisted to 8 float4 VGPRs (coalesced); x tile broadcast from LDS.
// ---------------------------------------------------------------------------
__global__ __launch_bounds__(256) void u_gemm2(const float* __restrict__ xin,
                                               const float* __restrict__ wbT,
                                               const float* __restrict__ bb,
                                               unsigned short* __restrict__ UT,
                                               float* __restrict__ xb) {
    __shared__ float xs[16 * C];
    const int b   = blockIdx.x;
    const int nb  = (b >> 2) * 16;
    const int o0  = (b & 3) * 8;
    const int tid = threadIdx.x;
    for (int t = tid; t < 16 * C; t += 256) xs[t] = xin[nb * C + t];
    __syncthreads();

    const int op = tid >> 5, k = tid & 31, o = o0 + op;
    float4v wv[8];
    const float* wp = wbT + ((size_t)o * C + k) * C;
#pragma unroll
    for (int i4 = 0; i4 < 8; ++i4)
        wv[i4] = *reinterpret_cast<const float4v*>(wp + i4 * 4);

#pragma unroll
    for (int n = 0; n < 16; ++n) {
        float acc = 0.f;
#pragma unroll
        for (int i4 = 0; i4 < 8; ++i4) {
            const float4v xv = *reinterpret_cast<const float4v*>(&xs[n * C + i4 * 4]);
            acc += xv.x * wv[i4].x + xv.y * wv[i4].y + xv.z * wv[i4].z + xv.w * wv[i4].w;
        }
        UT[(size_t)(nb + n) * (C * C) + o * C + k] = f2bf(acc);
    }
    if (o0 == 0) {
#pragma unroll
        for (int t = 0; t < 2; ++t) {
            const int idx = t * 256 + tid;
            const int n = idx >> 5, oo = idx & 31;
            float acc = 0.f;
#pragma unroll
            for (int i = 0; i < C; ++i) acc += xs[n * C + i] * bb[i * C + oo];
            xb[(nb + n) * C + oo] = acc;
        }
    }
}

// ---------------------------------------------------------------------------
// edge4_kernel: one wave per src; 16-edge groups via MFMA.
//   lane l: el = l&15 (edge row / o col), q = l>>4 (k-block)
//   A[el][q*8+j] = bf16(relu(ea[pb+el] @ wa + ba))  -- computed in-lane, no LDS
//   B1/B2 = U_T[src] halves, one 16B coalesced load each (bf16 direct)
//   D = mfma_f32_16x16x32_bf16(A, B, C=xb broadcast); masked coalesced atomics
// ---------------------------------------------------------------------------
__global__ __launch_bounds__(256) void edge4_kernel(const int* __restrict__ offs,
                                                    const int* __restrict__ dst_s,
                                                    const float* __restrict__ ea_s,
                                                    const float* __restrict__ wa,
                                                    const float* __restrict__ ba,
                                                    const unsigned short* __restrict__ UT,
                                                    const float* __restrict__ xb,
                                                    float* __restrict__ sumbuf) {
    __shared__ float was[ED * C];
    __shared__ float bas[C];
    const int tid = threadIdx.x;
    for (int t = tid; t < ED * C; t += 256) was[t] = wa[t];
    if (tid < C) bas[tid] = ba[tid];
    __syncthreads();

    const int w  = tid >> 6;
    const int l  = tid & 63;
    const int s  = blockIdx.x * 4 + w;     // 2500*4 == 10000
    const int q  = l >> 4;                 // k-block 0..3
    const int el = l & 15;                 // edge row / output col

    const int e0 = offs[s], e1 = offs[s + 1];
    if (e0 == e1) return;

    // B fragments: lane l holds U_T[src][col=el(+16)][k=q*8+j], j=0..7 (16B)
    const unsigned short* up = UT + (size_t)s * (C * C);
    const short8v B1 = *reinterpret_cast<const short8v*>(up + el * C + q * 8);
    const short8v B2 = *reinterpret_cast<const short8v*>(up + (el + 16) * C + q * 8);
    const float c1 = xb[s * C + el];
    const float c2 = xb[s * C + el + 16];
    const float4v C1 = {c1, c1, c1, c1};
    const float4v C2 = {c2, c2, c2, c2};
    float hb[8];
#pragma unroll
    for (int i = 0; i < 8; ++i) hb[i] = bas[q * 8 + i];

    for (int pb = e0; pb < e1; pb += 16) {
        const int p  = pb + el;
        const int pc = (p < e1) ? p : e0;          // clamp (masked at atomic)
        const float* eap = ea_s + (size_t)pc * EAP;
        const float4v ea0 = *reinterpret_cast<const float4v*>(eap);
        const float4v ea1 = *reinterpret_cast<const float4v*>(eap + 4);
        const float   ea8 = eap[8];

        float h[8];
#pragma unroll
        for (int i = 0; i < 8; ++i) h[i] = hb[i];
#pragma unroll
        for (int j = 0; j < ED; ++j) {
            const float ev = (j == 0) ? ea0.x : (j == 1) ? ea0.y : (j == 2) ? ea0.z
                           : (j == 3) ? ea0.w : (j == 4) ? ea1.x : (j == 5) ? ea1.y
                           : (j == 6) ? ea1.z : (j == 7) ? ea1.w : ea8;
            const float4v w0 = *reinterpret_cast<const float4v*>(&was[j * C + q * 8]);
            const float4v w1 = *reinterpret_cast<const float4v*>(&was[j * C + q * 8 + 4]);
            h[0] += ev * w0.x; h[1] += ev * w0.y; h[2] += ev * w0.z; h[3] += ev * w0.w;
            h[4] += ev * w1.x; h[5] += ev * w1.y; h[6] += ev * w1.z; h[7] += ev * w1.w;
        }
        union { int u[4]; short8v v; } A;
#pragma unroll
        for (int v = 0; v < 4; ++v) {
            const unsigned lo = f2bf(fmaxf(h[2 * v], 0.f));
            const unsigned hi = f2bf(fmaxf(h[2 * v + 1], 0.f));
            A.u[v] = (int)(lo | (hi << 16));
        }
        const float4v d1 = __builtin_amdgcn_mfma_f32_16x16x32_bf16(A.v, B1, C1, 0, 0, 0);
        const float4v d2 = __builtin_amdgcn_mfma_f32_16x16x32_bf16(A.v, B2, C2, 0, 0, 0);
#pragma unroll
        for (int r = 0; r < 4; ++r) {
            const int pe = pb + q * 4 + r;          // D row = (l>>4)*4 + r
            if (pe < e1) {
                const int dst = dst_s[pe];
                atomicAdd(&sumbuf[(size_t)dst * C + el],      d1[r]);
                atomicAdd(&sumbuf[(size_t)dst * C + el + 16], d2[r]);
            }
        }
    }
}

// ---------------------------------------------------------------------------
// node_kernel: out[n,o] = relu(sum[n,o]/max(cnt,1) + sum_i xin[n,i]*root[i,o] + bias[o])
// ---------------------------------------------------------------------------
__global__ __launch_bounds__(256) void node_kernel(const float* __restrict__ xin,
                                                   const float* __restrict__ sumbuf,
                                                   const int* __restrict__ cnt,
                                                   const float* __restrict__ root,
                                                   const float* __restrict__ bias,
                                                   float* __restrict__ outb) {
    __shared__ float rs[C * C];
    __shared__ float bs[C];
    __shared__ float xs[8][C];
    const int tid = threadIdx.x;
    for (int t = tid; t < C * C; t += 256) rs[t] = root[t];
    if (tid < C) bs[tid] = bias[tid];
    const int nl = tid >> 5, o = tid & 31;
    const int n  = blockIdx.x * 8 + nl;
    xs[nl][o] = (n < NN) ? xin[n * C + o] : 0.f;
    __syncthreads();
    if (n < NN) {
        float acc = bs[o];
#pragma unroll
        for (int i = 0; i < C; ++i) acc += xs[nl][i] * rs[i * C + o];
        const float cn = fmaxf((float)cnt[n], 1.f);
        acc += sumbuf[n * C + o] / cn;
        outb[n * C + o] = fmaxf(acc, 0.f);
    }
}

// ---------------------------------------------------------------------------
__global__ __launch_bounds__(256) void score_kernel(const float* __restrict__ h,
                                                    const float* __restrict__ emb,
                                                    const int* __restrict__ signal,
                                                    float* __restrict__ scores) {
    __shared__ float sig[C];
    if (threadIdx.x < C) sig[threadIdx.x] = emb[(size_t)signal[0] * C + threadIdx.x];
    __syncthreads();
    const int n = blockIdx.x * 256 + threadIdx.x;
    if (n < NN) {
        float acc = 0.f;
#pragma unroll
        for (int o = 0; o < C; ++o) acc += h[n * C + o] * sig[o];
        scores[n] = acc;
    }
}

__global__ __launch_bounds__(1024) void reduce_kernel(const float* __restrict__ scores,
                                                      float* __restrict__ red) {
    __shared__ float sm[16];
    __shared__ float ss[16];
    const int tid = threadIdx.x;
    float m = -INFINITY;
    for (int n = tid; n < NN; n += 1024) m = fmaxf(m, scores[n]);
    for (int off = 32; off; off >>= 1) m = fmaxf(m, __shfl_down(m, off, 64));
    if ((tid & 63) == 0) sm[tid >> 6] = m;
    __syncthreads();
    if (tid == 0) {
        float mm = sm[0];
        for (int w = 1; w < 16; ++w) mm = fmaxf(mm, sm[w]);
        sm[0] = mm;
    }
    __syncthreads();
    const float gmax = sm[0];
    float s = 0.f;
    for (int n = tid; n < NN; n += 1024) s += expf(scores[n] - gmax);
    for (int off = 32; off; off >>= 1) s += __shfl_down(s, off, 64);
    if ((tid & 63) == 0) ss[tid >> 6] = s;
    __syncthreads();
    if (tid == 0) {
        float t = 0.f;
        for (int w = 0; w < 16; ++w) t += ss[w];
        red[0] = gmax;
        red[1] = logf(t);
    }
}

__global__ __launch_bounds__(256) void out_kernel(const float* __restrict__ scores,
                                                  const float* __restrict__ red,
                                                  float* __restrict__ out) {
    const int n = blockIdx.x * 256 + threadIdx.x;
    if (n < NN) out[n] = scores[n] - red[0] - red[1];
}

// ---------------------------------------------------------------------------
extern "C" void kernel_launch(void* const* d_in, const int* in_sizes, int n_in,
                              void* d_out, int out_size, void* d_ws, size_t ws_size,
                              hipStream_t stream) {
    const int*   signal = (const int*)d_in[0];
    const float* x      = (const float*)d_in[1];
    const int*   ei     = (const int*)d_in[2];
    const float* ea     = (const float*)d_in[3];
    const float* w1a    = (const float*)d_in[4];
    const float* b1a    = (const float*)d_in[5];
    const float* w1b    = (const float*)d_in[6];
    const float* b1b    = (const float*)d_in[7];
    const float* root1  = (const float*)d_in[8];
    const float* bias1  = (const float*)d_in[9];
    const float* w2a    = (const float*)d_in[10];
    const float* b2a    = (const float*)d_in[11];
    const float* w2b    = (const float*)d_in[12];
    const float* b2b    = (const float*)d_in[13];
    const float* root2  = (const float*)d_in[14];
    const float* bias2  = (const float*)d_in[15];
    const float* emb    = (const float*)d_in[16];

    // ---- workspace layout ----
    float* ws = (float*)d_ws;
    unsigned short* UT = (unsigned short*)ws;         // 10,240,000 bf16 (20.5 MB)
    float* xb     = ws + 5120000;                     // 320,000
    float* sumbuf = xb + NN * C;                      // 320,000
    float* h1     = sumbuf + NN * C;                  // 320,000
    float* h2     = h1 + NN * C;                      // 320,000
    float* ea_s   = h2 + NN * C;                      // NE*EAP = 1,920,000
    float* wbT1   = ea_s + (size_t)NE * EAP;          // 32,768
    float* wbT2   = wbT1 + 32768;                     // 32,768
    float* scores = wbT2 + 32768;                     // 10,000
    float* red    = scores + NN;                      // 16
    int*   cnt_src = (int*)(red + 16);                // 10,000 \  zeroed in
    int*   cnt_dst = cnt_src + NN;                    // 10,000  | one memset
    int*   cursor  = cnt_dst + NN;                    // 10,000 /
    int*   offs    = cursor + NN;                     // 10,016
    int*   dst_s   = offs + NN + 16;                  // 160,000

    hipMemsetAsync(cnt_src, 0, 3 * NN * sizeof(int), stream);
    hipMemsetAsync(sumbuf, 0, NN * C * sizeof(float), stream);

    // ---- CSR by src (reused by both convs) + wb transposes ----
    hist_kernel<<<(NE + 255) / 256, 256, 0, stream>>>(ei, cnt_src, cnt_dst);
    scan_kernel<<<1, 1024, 0, stream>>>(cnt_src, offs);
    scatter_kernel<<<(NE + 255) / 256, 256, 0, stream>>>(ei, ea, offs, cursor, dst_s, ea_s);
    wbt_kernel<<<128, 256, 0, stream>>>(w1b, wbT1);
    wbt_kernel<<<128, 256, 0, stream>>>(w2b, wbT2);

    // ---- conv1 ----
    u_gemm2<<<2500, 256, 0, stream>>>(x, wbT1, b1b, UT, xb);
    edge4_kernel<<<2500, 256, 0, stream>>>(offs, dst_s, ea_s, w1a, b1a, UT, xb, sumbuf);
    node_kernel<<<NN / 8, 256, 0, stream>>>(x, sumbuf, cnt_dst, root1, bias1, h1);

    // ---- conv2 ----
    hipMemsetAsync(sumbuf, 0, NN * C * sizeof(float), stream);
    u_gemm2<<<2500, 256, 0, stream>>>(h1, wbT2, b2b, UT, xb);
    edge4_kernel<<<2500, 256, 0, stream>>>(offs, dst_s, ea_s, w2a, b2a, UT, xb, sumbuf);
    node_kernel<<<NN / 8, 256, 0, stream>>>(h1, sumbuf, cnt_dst, root2, bias2, h2);

    // ---- readout ----
    score_kernel<<<(NN + 255) / 256, 256, 0, stream>>>(h2, emb, signal, scores);
    reduce_kernel<<<1, 1024, 0, stream>>>(scores, red);
    out_kernel<<<(NN + 255) / 256, 256, 0, stream>>>(scores, red, (float*)d_out);
}

// Round 5
// 178.930 us; speedup vs baseline: 1.7101x; 1.0223x over previous
//
#include <hip/hip_runtime.h>
#include <math.h>

#define NN 10000      // nodes
#define NE 160000     // edges
#define C  32         // FEAT == EMB == HID == 32
#define ED 9          // edge feature dim
#define EAP 12        // padded edge-attr stride (16B-aligned float4 loads)

typedef __attribute__((ext_vector_type(8))) short short8v;   // 8 bf16 (4 VGPR)
typedef __attribute__((ext_vector_type(4))) float float4v;

__device__ inline unsigned short f2bf(float f) {        // fp32 -> bf16 RNE
    unsigned int u = __float_as_uint(f);
    return (unsigned short)((u + 0x7fffu + ((u >> 16) & 1u)) >> 16);
}

// ---------------------------------------------------------------------------
// zfill_kernel: zero a contiguous region (uint4 stores). Replaces the ROCm
// fillBufferAligned (measured 43 us / 29 GB/s for 1.25 MB in graph replay).
// ---------------------------------------------------------------------------
__global__ __launch_bounds__(256) void zfill_kernel(uint4* __restrict__ p, int n16) {
    const int i = blockIdx.x * 256 + threadIdx.x;
    if (i < n16) p[i] = uint4{0u, 0u, 0u, 0u};
}

// ---------------------------------------------------------------------------
// hist_kernel: out-degree histogram (src) for CSR + in-degree (dst) for mean
// ---------------------------------------------------------------------------
__global__ __launch_bounds__(256) void hist_kernel(const int* __restrict__ ei,
                                                   int* __restrict__ cnt_src,
                                                   int* __restrict__ cnt_dst) {
    const int e = blockIdx.x * 256 + threadIdx.x;
    if (e < NE) {
        atomicAdd(&cnt_src[ei[e]], 1);
        atomicAdd(&cnt_dst[ei[NE + e]], 1);
    }
}

// ---------------------------------------------------------------------------
// scan_kernel: exclusive prefix sum of cnt_src[10000] -> offs[10001]
// ---------------------------------------------------------------------------
__global__ __launch_bounds__(1024) void scan_kernel(const int* __restrict__ cnt,
                                                    int* __restrict__ offs) {
    __shared__ int part[1024];
    const int t = threadIdx.x;
    const int base = t * 10;
    int loc[10];
    int s = 0;
#pragma unroll
    for (int j = 0; j < 10; ++j) {
        int v = (base + j < NN) ? cnt[base + j] : 0;
        loc[j] = s;
        s += v;
    }
    part[t] = s;
    __syncthreads();
    for (int off = 1; off < 1024; off <<= 1) {
        int v = (t >= off) ? part[t - off] : 0;
        __syncthreads();
        part[t] += v;
        __syncthreads();
    }
    const int excl = (t == 0) ? 0 : part[t - 1];
#pragma unroll
    for (int j = 0; j < 10; ++j)
        if (base + j < NN) offs[base + j] = excl + loc[j];
    if (t == 1023) offs[NN] = part[1023];
}

// ---------------------------------------------------------------------------
// scatter_kernel: build CSR payload sorted by src (ea padded to stride 12)
// ---------------------------------------------------------------------------
__global__ __launch_bounds__(256) void scatter_kernel(const int* __restrict__ ei,
                                                      const float* __restrict__ ea,
                                                      const int* __restrict__ offs,
                                                      int* __restrict__ cursor,
                                                      int* __restrict__ dst_s,
                                                      float* __restrict__ ea_s) {
    const int e = blockIdx.x * 256 + threadIdx.x;
    if (e < NE) {
        const int b   = ei[e];
        const int pos = offs[b] + atomicAdd(&cursor[b], 1);
        dst_s[pos] = ei[NE + e];
#pragma unroll
        for (int j = 0; j < ED; ++j)
            ea_s[(size_t)pos * EAP + j] = ea[(size_t)e * ED + j];
    }
}

// ---------------------------------------------------------------------------
// wbt_kernel: wbT[o*1024 + k*32 + i] = wb[k*1024 + i*32 + o]
// ---------------------------------------------------------------------------
__global__ __launch_bounds__(256) void wbt_kernel(const float* __restrict__ wb,
                                                  float* __restrict__ wbT) {
    const int idx = blockIdx.x * 256 + threadIdx.x;   // 0..32767
    const int i = idx & 31, k = (idx >> 5) & 31, o = idx >> 10;
    wbT[idx] = wb[k * (C * C) + i * C + o];
}

// ---------------------------------------------------------------------------
// u_gemm2: U_T[n][o][k] = f2bf(sum_i xin[n,i] * wb[k, i*32+o])
//          xb[n][o]     = sum_i xin[n,i] * bb[i*32+o]
// ---------------------------------------------------------------------------
__global__ __launch_bounds__(256) void u_gemm2(const float* __restrict__ xin,
                                               const float* __restrict__ wbT,
                                               const float* __restrict__ bb,
                                               unsigned short* __restrict__ UT,
                                               float* __restrict__ xb) {
    __shared__ float xs[16 * C];
    const int b   = blockIdx.x;
    const int nb  = (b >> 2) * 16;
    const int o0  = (b & 3) * 8;
    const int tid = threadIdx.x;
    for (int t = tid; t < 16 * C; t += 256) xs[t] = xin[nb * C + t];
    __syncthreads();

    const int op = tid >> 5, k = tid & 31, o = o0 + op;
    float4v wv[8];
    const float* wp = wbT + ((size_t)o * C + k) * C;
#pragma unroll
    for (int i4 = 0; i4 < 8; ++i4)
        wv[i4] = *reinterpret_cast<const float4v*>(wp + i4 * 4);

#pragma unroll
    for (int n = 0; n < 16; ++n) {
        float acc = 0.f;
#pragma unroll
        for (int i4 = 0; i4 < 8; ++i4) {
            const float4v xv = *reinterpret_cast<const float4v*>(&xs[n * C + i4 * 4]);
            acc += xv.x * wv[i4].x + xv.y * wv[i4].y + xv.z * wv[i4].z + xv.w * wv[i4].w;
        }
        UT[(size_t)(nb + n) * (C * C) + o * C + k] = f2bf(acc);
    }
    if (o0 == 0) {
#pragma unroll
        for (int t = 0; t < 2; ++t) {
            const int idx = t * 256 + tid;
            const int n = idx >> 5, oo = idx & 31;
            float acc = 0.f;
#pragma unroll
            for (int i = 0; i < C; ++i) acc += xs[n * C + i] * bb[i * C + oo];
            xb[(nb + n) * C + oo] = acc;
        }
    }
}

// ---------------------------------------------------------------------------
// edge4_kernel: one wave per src; 16-edge groups via MFMA.
// ---------------------------------------------------------------------------
__global__ __launch_bounds__(256) void edge4_kernel(const int* __restrict__ offs,
                                                    const int* __restrict__ dst_s,
                                                    const float* __restrict__ ea_s,
                                                    const float* __restrict__ wa,
                                                    const float* __restrict__ ba,
                                                    const unsigned short* __restrict__ UT,
                                                    const float* __restrict__ xb,
                                                    float* __restrict__ sumbuf) {
    __shared__ float was[ED * C];
    __shared__ float bas[C];
    const int tid = threadIdx.x;
    for (int t = tid; t < ED * C; t += 256) was[t] = wa[t];
    if (tid < C) bas[tid] = ba[tid];
    __syncthreads();

    const int w  = tid >> 6;
    const int l  = tid & 63;
    const int s  = blockIdx.x * 4 + w;     // 2500*4 == 10000
    const int q  = l >> 4;                 // k-block 0..3
    const int el = l & 15;                 // edge row / output col

    const int e0 = offs[s], e1 = offs[s + 1];
    if (e0 == e1) return;

    const unsigned short* up = UT + (size_t)s * (C * C);
    const short8v B1 = *reinterpret_cast<const short8v*>(up + el * C + q * 8);
    const short8v B2 = *reinterpret_cast<const short8v*>(up + (el + 16) * C + q * 8);
    const float c1 = xb[s * C + el];
    const float c2 = xb[s * C + el + 16];
    const float4v C1 = {c1, c1, c1, c1};
    const float4v C2 = {c2, c2, c2, c2};
    float hb[8];
#pragma unroll
    for (int i = 0; i < 8; ++i) hb[i] = bas[q * 8 + i];

    for (int pb = e0; pb < e1; pb += 16) {
        const int p  = pb + el;
        const int pc = (p < e1) ? p : e0;          // clamp (masked at atomic)
        const float* eap = ea_s + (size_t)pc * EAP;
        const float4v ea0 = *reinterpret_cast<const float4v*>(eap);
        const float4v ea1 = *reinterpret_cast<const float4v*>(eap + 4);
        const float   ea8 = eap[8];

        float h[8];
#pragma unroll
        for (int i = 0; i < 8; ++i) h[i] = hb[i];
#pragma unroll
        for (int j = 0; j < ED; ++j) {
            const float ev = (j == 0) ? ea0.x : (j == 1) ? ea0.y : (j == 2) ? ea0.z
                           : (j == 3) ? ea0.w : (j == 4) ? ea1.x : (j == 5) ? ea1.y
                           : (j == 6) ? ea1.z : (j == 7) ? ea1.w : ea8;
            const float4v w0 = *reinterpret_cast<const float4v*>(&was[j * C + q * 8]);
            const float4v w1 = *reinterpret_cast<const float4v*>(&was[j * C + q * 8 + 4]);
            h[0] += ev * w0.x; h[1] += ev * w0.y; h[2] += ev * w0.z; h[3] += ev * w0.w;
            h[4] += ev * w1.x; h[5] += ev * w1.y; h[6] += ev * w1.z; h[7] += ev * w1.w;
        }
        union { int u[4]; short8v v; } A;
#pragma unroll
        for (int v = 0; v < 4; ++v) {
            const unsigned lo = f2bf(fmaxf(h[2 * v], 0.f));
            const unsigned hi = f2bf(fmaxf(h[2 * v + 1], 0.f));
            A.u[v] = (int)(lo | (hi << 16));
        }
        const float4v d1 = __builtin_amdgcn_mfma_f32_16x16x32_bf16(A.v, B1, C1, 0, 0, 0);
        const float4v d2 = __builtin_amdgcn_mfma_f32_16x16x32_bf16(A.v, B2, C2, 0, 0, 0);
#pragma unroll
        for (int r = 0; r < 4; ++r) {
            const int pe = pb + q * 4 + r;          // D row = (l>>4)*4 + r
            if (pe < e1) {
                const int dst = dst_s[pe];
                atomicAdd(&sumbuf[(size_t)dst * C + el],      d1[r]);
                atomicAdd(&sumbuf[(size_t)dst * C + el + 16], d2[r]);
            }
        }
    }
}

// ---------------------------------------------------------------------------
// node_kernel
// ---------------------------------------------------------------------------
__global__ __launch_bounds__(256) void node_kernel(const float* __restrict__ xin,
                                                   const float* __restrict__ sumbuf,
                                                   const int* __restrict__ cnt,
                                                   const float* __restrict__ root,
                                                   const float* __restrict__ bias,
                                                   float* __restrict__ outb) {
    __shared__ float rs[C * C];
    __shared__ float bs[C];
    __shared__ float xs[8][C];
    const int tid = threadIdx.x;
    for (int t = tid; t < C * C; t += 256) rs[t] = root[t];
    if (tid < C) bs[tid] = bias[tid];
    const int nl = tid >> 5, o = tid & 31;
    const int n  = blockIdx.x * 8 + nl;
    xs[nl][o] = (n < NN) ? xin[n * C + o] : 0.f;
    __syncthreads();
    if (n < NN) {
        float acc = bs[o];
#pragma unroll
        for (int i = 0; i < C; ++i) acc += xs[nl][i] * rs[i * C + o];
        const float cn = fmaxf((float)cnt[n], 1.f);
        acc += sumbuf[n * C + o] / cn;
        outb[n * C + o] = fmaxf(acc, 0.f);
    }
}

// ---------------------------------------------------------------------------
__global__ __launch_bounds__(256) void score_kernel(const float* __restrict__ h,
                                                    const float* __restrict__ emb,
                                                    const int* __restrict__ signal,
                                                    float* __restrict__ scores) {
    __shared__ float sig[C];
    if (threadIdx.x < C) sig[threadIdx.x] = emb[(size_t)signal[0] * C + threadIdx.x];
    __syncthreads();
    const int n = blockIdx.x * 256 + threadIdx.x;
    if (n < NN) {
        float acc = 0.f;
#pragma unroll
        for (int o = 0; o < C; ++o) acc += h[n * C + o] * sig[o];
        scores[n] = acc;
    }
}

__global__ __launch_bounds__(1024) void reduce_kernel(const float* __restrict__ scores,
                                                      float* __restrict__ red) {
    __shared__ float sm[16];
    __shared__ float ss[16];
    const int tid = threadIdx.x;
    float m = -INFINITY;
    for (int n = tid; n < NN; n += 1024) m = fmaxf(m, scores[n]);
    for (int off = 32; off; off >>= 1) m = fmaxf(m, __shfl_down(m, off, 64));
    if ((tid & 63) == 0) sm[tid >> 6] = m;
    __syncthreads();
    if (tid == 0) {
        float mm = sm[0];
        for (int w = 1; w < 16; ++w) mm = fmaxf(mm, sm[w]);
        sm[0] = mm;
    }
    __syncthreads();
    const float gmax = sm[0];
    float s = 0.f;
    for (int n = tid; n < NN; n += 1024) s += expf(scores[n] - gmax);
    for (int off = 32; off; off >>= 1) s += __shfl_down(s, off, 64);
    if ((tid & 63) == 0) ss[tid >> 6] = s;
    __syncthreads();
    if (tid == 0) {
        float t = 0.f;
        for (int w = 0; w < 16; ++w) t += ss[w];
        red[0] = gmax;
        red[1] = logf(t);
    }
}

__global__ __launch_bounds__(256) void out_kernel(const float* __restrict__ scores,
                                                  const float* __restrict__ red,
                                                  float* __restrict__ out) {
    const int n = blockIdx.x * 256 + threadIdx.x;
    if (n < NN) out[n] = scores[n] - red[0] - red[1];
}

// ---------------------------------------------------------------------------
extern "C" void kernel_launch(void* const* d_in, const int* in_sizes, int n_in,
                              void* d_out, int out_size, void* d_ws, size_t ws_size,
                              hipStream_t stream) {
    const int*   signal = (const int*)d_in[0];
    const float* x      = (const float*)d_in[1];
    const int*   ei     = (const int*)d_in[2];
    const float* ea     = (const float*)d_in[3];
    const float* w1a    = (const float*)d_in[4];
    const float* b1a    = (const float*)d_in[5];
    const float* w1b    = (const float*)d_in[6];
    const float* b1b    = (const float*)d_in[7];
    const float* root1  = (const float*)d_in[8];
    const float* bias1  = (const float*)d_in[9];
    const float* w2a    = (const float*)d_in[10];
    const float* b2a    = (const float*)d_in[11];
    const float* w2b    = (const float*)d_in[12];
    const float* b2b    = (const float*)d_in[13];
    const float* root2  = (const float*)d_in[14];
    const float* bias2  = (const float*)d_in[15];
    const float* emb    = (const float*)d_in[16];

    // ---- workspace layout ----
    float* ws = (float*)d_ws;
    unsigned short* UT = (unsigned short*)ws;         // 10,240,000 bf16 (20.5 MB)
    float* xb      = ws + 5120000;                    // 320,000
    float* h1      = xb + NN * C;                     // 320,000
    float* h2      = h1 + NN * C;                     // 320,000
    float* ea_s    = h2 + NN * C;                     // NE*EAP = 1,920,000
    float* wbT1    = ea_s + (size_t)NE * EAP;         // 32,768
    float* wbT2    = wbT1 + 32768;                    // 32,768
    float* scores  = wbT2 + 32768;                    // 10,000
    float* red     = scores + NN;                     // 16
    // ---- contiguous zero region (zeroed by zfill_kernel each call) ----
    float* sumbuf1 = red + 16;                        // 320,000
    float* sumbuf2 = sumbuf1 + NN * C;                // 320,000
    int*   cnt_src = (int*)(sumbuf2 + NN * C);        // 10,000
    int*   cnt_dst = cnt_src + NN;                    // 10,000
    int*   cursor  = cnt_dst + NN;                    // 10,000
    // ---- end zero region: 670,000 words == 167,500 uint4 ----
    int*   offs    = cursor + NN;                     // 10,016
    int*   dst_s   = offs + NN + 16;                  // 160,000

    const int n16 = 167500;                           // (2*NN*C + 3*NN) / 4
    zfill_kernel<<<(n16 + 255) / 256, 256, 0, stream>>>((uint4*)sumbuf1, n16);

    // ---- CSR by src (reused by both convs) + wb transposes ----
    hist_kernel<<<(NE + 255) / 256, 256, 0, stream>>>(ei, cnt_src, cnt_dst);
    scan_kernel<<<1, 1024, 0, stream>>>(cnt_src, offs);
    scatter_kernel<<<(NE + 255) / 256, 256, 0, stream>>>(ei, ea, offs, cursor, dst_s, ea_s);
    wbt_kernel<<<128, 256, 0, stream>>>(w1b, wbT1);
    wbt_kernel<<<128, 256, 0, stream>>>(w2b, wbT2);

    // ---- conv1 ----
    u_gemm2<<<2500, 256, 0, stream>>>(x, wbT1, b1b, UT, xb);
    edge4_kernel<<<2500, 256, 0, stream>>>(offs, dst_s, ea_s, w1a, b1a, UT, xb, sumbuf1);
    node_kernel<<<NN / 8, 256, 0, stream>>>(x, sumbuf1, cnt_dst, root1, bias1, h1);

    // ---- conv2 ----
    u_gemm2<<<2500, 256, 0, stream>>>(h1, wbT2, b2b, UT, xb);
    edge4_kernel<<<2500, 256, 0, stream>>>(offs, dst_s, ea_s, w2a, b2a, UT, xb, sumbuf2);
    node_kernel<<<NN / 8, 256, 0, stream>>>(h1, sumbuf2, cnt_dst, root2, bias2, h2);

    // ---- readout ----
    score_kernel<<<(NN + 255) / 256, 256, 0, stream>>>(h2, emb, signal, scores);
    reduce_kernel<<<1, 1024, 0, stream>>>(scores, red);
    out_kernel<<<(NN + 255) / 256, 256, 0, stream>>>(scores, red, (float*)d_out);
}

// Round 6
// 161.118 us; speedup vs baseline: 1.8992x; 1.1105x over previous
//
#include <hip/hip_runtime.h>
#include <math.h>

#define NN 10000      // nodes
#define NE 160000     // edges
#define C  32         // FEAT == EMB == HID == 32
#define ED 9          // edge feature dim
#define EAP 12        // padded edge-attr stride (16B-aligned float4 loads)

typedef __attribute__((ext_vector_type(8))) short short8v;   // 8 bf16 (4 VGPR)
typedef __attribute__((ext_vector_type(4))) float float4v;

__device__ inline unsigned short f2bf(float f) {        // fp32 -> bf16 RNE
    unsigned int u = __float_as_uint(f);
    return (unsigned short)((u + 0x7fffu + ((u >> 16) & 1u)) >> 16);
}

// ---------------------------------------------------------------------------
// prep_kernel: blocks [0,655) zero the atomic region (uint4 stores);
//              blocks [655,783) transpose w1b; [783,911) transpose w2b.
// wbT[o*1024 + k*32 + i] = wb[k*1024 + i*32 + o]
// ---------------------------------------------------------------------------
#define ZB 655        // ceil(167500/256)
__global__ __launch_bounds__(256) void prep_kernel(uint4* __restrict__ zreg, int n16,
                                                   const float* __restrict__ w1b,
                                                   const float* __restrict__ w2b,
                                                   float* __restrict__ wbT1,
                                                   float* __restrict__ wbT2) {
    const int b = blockIdx.x, tid = threadIdx.x;
    if (b < ZB) {
        const int i = b * 256 + tid;
        if (i < n16) zreg[i] = uint4{0u, 0u, 0u, 0u};
    } else if (b < ZB + 128) {
        const int idx = (b - ZB) * 256 + tid;             // 0..32767
        const int i = idx & 31, k = (idx >> 5) & 31, o = idx >> 10;
        wbT1[idx] = w1b[k * (C * C) + i * C + o];
    } else {
        const int idx = (b - ZB - 128) * 256 + tid;
        const int i = idx & 31, k = (idx >> 5) & 31, o = idx >> 10;
        wbT2[idx] = w2b[k * (C * C) + i * C + o];
    }
}

// ---------------------------------------------------------------------------
// hist_kernel: out-degree histogram (src) for CSR + in-degree (dst) for mean
// ---------------------------------------------------------------------------
__global__ __launch_bounds__(256) void hist_kernel(const int* __restrict__ ei,
                                                   int* __restrict__ cnt_src,
                                                   int* __restrict__ cnt_dst) {
    const int e = blockIdx.x * 256 + threadIdx.x;
    if (e < NE) {
        atomicAdd(&cnt_src[ei[e]], 1);
        atomicAdd(&cnt_dst[ei[NE + e]], 1);
    }
}

// ---------------------------------------------------------------------------
// scan_kernel: exclusive prefix sum of cnt_src[10000] -> offs[10001]
// wave-shuffle scan: 2 barriers total (vs 20 in Hillis-Steele version)
// ---------------------------------------------------------------------------
__global__ __launch_bounds__(1024) void scan_kernel(const int* __restrict__ cnt,
                                                    int* __restrict__ offs) {
    __shared__ int wtot[16];
    const int t = threadIdx.x;
    const int lane = t & 63, wid = t >> 6;
    const int base = t * 10;
    int loc[10];
    int s = 0;
#pragma unroll
    for (int j = 0; j < 10; ++j) {
        int v = (base + j < NN) ? cnt[base + j] : 0;
        loc[j] = s;
        s += v;
    }
    int inc = s;                                   // wave-inclusive scan
    for (int d = 1; d < 64; d <<= 1) {
        int v = __shfl_up(inc, d, 64);
        if (lane >= d) inc += v;
    }
    if (lane == 63) wtot[wid] = inc;
    __syncthreads();
    if (t < 16) {
        int w = wtot[t];
        for (int d = 1; d < 16; d <<= 1) {
            int v = __shfl_up(w, d, 64);
            if (t >= d) w += v;
        }
        wtot[t] = w;
    }
    __syncthreads();
    const int excl = inc - s + (wid ? wtot[wid - 1] : 0);
#pragma unroll
    for (int j = 0; j < 10; ++j)
        if (base + j < NN) offs[base + j] = excl + loc[j];
    if (t == 1023) offs[NN] = wtot[15];
}

// ---------------------------------------------------------------------------
// scatter_kernel: build CSR payload sorted by src (ea padded to stride 12)
// ---------------------------------------------------------------------------
__global__ __launch_bounds__(256) void scatter_kernel(const int* __restrict__ ei,
                                                      const float* __restrict__ ea,
                                                      const int* __restrict__ offs,
                                                      int* __restrict__ cursor,
                                                      int* __restrict__ dst_s,
                                                      float* __restrict__ ea_s) {
    const int e = blockIdx.x * 256 + threadIdx.x;
    if (e < NE) {
        const int b   = ei[e];
        const int pos = offs[b] + atomicAdd(&cursor[b], 1);
        dst_s[pos] = ei[NE + e];
#pragma unroll
        for (int j = 0; j < ED; ++j)
            ea_s[(size_t)pos * EAP + j] = ea[(size_t)e * ED + j];
    }
}

// ---------------------------------------------------------------------------
// u_gemm2: U_T[n][o][k] = f2bf(sum_i xin[n,i] * wb[k, i*32+o])
//          xb[n][o]     = sum_i xin[n,i] * bb[i*32+o]
// 2500 blocks: (16 nodes) x (8-of-32 o cols). conv1 only.
// ---------------------------------------------------------------------------
__global__ __launch_bounds__(256) void u_gemm2(const float* __restrict__ xin,
                                               const float* __restrict__ wbT,
                                               const float* __restrict__ bb,
                                               unsigned short* __restrict__ UT,
                                               float* __restrict__ xb) {
    __shared__ float xs[16 * C];
    const int b   = blockIdx.x;
    const int nb  = (b >> 2) * 16;
    const int o0  = (b & 3) * 8;
    const int tid = threadIdx.x;
    for (int t = tid; t < 16 * C; t += 256) xs[t] = xin[nb * C + t];
    __syncthreads();

    const int op = tid >> 5, k = tid & 31, o = o0 + op;
    float4v wv[8];
    const float* wp = wbT + ((size_t)o * C + k) * C;
#pragma unroll
    for (int i4 = 0; i4 < 8; ++i4)
        wv[i4] = *reinterpret_cast<const float4v*>(wp + i4 * 4);

#pragma unroll
    for (int n = 0; n < 16; ++n) {
        float acc = 0.f;
#pragma unroll
        for (int i4 = 0; i4 < 8; ++i4) {
            const float4v xv = *reinterpret_cast<const float4v*>(&xs[n * C + i4 * 4]);
            acc += xv.x * wv[i4].x + xv.y * wv[i4].y + xv.z * wv[i4].z + xv.w * wv[i4].w;
        }
        UT[(size_t)(nb + n) * (C * C) + o * C + k] = f2bf(acc);
    }
    if (o0 == 0) {
#pragma unroll
        for (int t = 0; t < 2; ++t) {
            const int idx = t * 256 + tid;
            const int n = idx >> 5, oo = idx & 31;
            float acc = 0.f;
#pragma unroll
            for (int i = 0; i < C; ++i) acc += xs[n * C + i] * bb[i * C + oo];
            xb[(nb + n) * C + oo] = acc;
        }
    }
}

// ---------------------------------------------------------------------------
// u_gemm2_fused (conv2): computes the h1 tile in-LDS from conv1's aggregates
//   h1[n,o] = relu(sumbuf1[n,o]/max(cnt,1) + x[n,:]@root1[:,o] + bias1[o])
// then the same U/xb products as u_gemm2, reading h1 from LDS.
// o0==0 blocks also write h1 to global (needed by node2_score).
// ---------------------------------------------------------------------------
__global__ __launch_bounds__(256) void u_gemm2_fused(const float* __restrict__ xin,
                                                     const float* __restrict__ sumbuf1,
                                                     const int* __restrict__ cnt,
                                                     const float* __restrict__ root1,
                                                     const float* __restrict__ bias1,
                                                     const float* __restrict__ wbT,
                                                     const float* __restrict__ bb,
                                                     unsigned short* __restrict__ UT,
                                                     float* __restrict__ xb,
                                                     float* __restrict__ h1out) {
    __shared__ float xs[16 * C];
    __shared__ float hs[16 * C];
    const int b   = blockIdx.x;
    const int nb  = (b >> 2) * 16;
    const int o0  = (b & 3) * 8;
    const int tid = threadIdx.x;
    for (int t = tid; t < 16 * C; t += 256) xs[t] = xin[nb * C + t];
    __syncthreads();

    // ---- h1 tile: 512 outputs, 2 per thread ----
#pragma unroll
    for (int t = 0; t < 2; ++t) {
        const int idx = t * 256 + tid;
        const int n = idx >> 5, oo = idx & 31;
        float acc = bias1[oo];
#pragma unroll
        for (int i = 0; i < C; ++i) acc += xs[n * C + i] * root1[i * C + oo];
        const float cn = fmaxf((float)cnt[nb + n], 1.f);
        acc += sumbuf1[(size_t)(nb + n) * C + oo] / cn;
        const float h = fmaxf(acc, 0.f);
        hs[n * C + oo] = h;
        if (o0 == 0) h1out[(size_t)(nb + n) * C + oo] = h;
    }
    __syncthreads();

    const int op = tid >> 5, k = tid & 31, o = o0 + op;
    float4v wv[8];
    const float* wp = wbT + ((size_t)o * C + k) * C;
#pragma unroll
    for (int i4 = 0; i4 < 8; ++i4)
        wv[i4] = *reinterpret_cast<const float4v*>(wp + i4 * 4);

#pragma unroll
    for (int n = 0; n < 16; ++n) {
        float acc = 0.f;
#pragma unroll
        for (int i4 = 0; i4 < 8; ++i4) {
            const float4v xv = *reinterpret_cast<const float4v*>(&hs[n * C + i4 * 4]);
            acc += xv.x * wv[i4].x + xv.y * wv[i4].y + xv.z * wv[i4].z + xv.w * wv[i4].w;
        }
        UT[(size_t)(nb + n) * (C * C) + o * C + k] = f2bf(acc);
    }
    if (o0 == 0) {
#pragma unroll
        for (int t = 0; t < 2; ++t) {
            const int idx = t * 256 + tid;
            const int n = idx >> 5, oo = idx & 31;
            float acc = 0.f;
#pragma unroll
            for (int i = 0; i < C; ++i) acc += hs[n * C + i] * bb[i * C + oo];
            xb[(size_t)(nb + n) * C + oo] = acc;
        }
    }
}

// ---------------------------------------------------------------------------
// edge4_kernel: one wave per src; 16-edge groups via MFMA (unchanged).
// ---------------------------------------------------------------------------
__global__ __launch_bounds__(256) void edge4_kernel(const int* __restrict__ offs,
                                                    const int* __restrict__ dst_s,
                                                    const float* __restrict__ ea_s,
                                                    const float* __restrict__ wa,
                                                    const float* __restrict__ ba,
                                                    const unsigned short* __restrict__ UT,
                                                    const float* __restrict__ xb,
                                                    float* __restrict__ sumbuf) {
    __shared__ float was[ED * C];
    __shared__ float bas[C];
    const int tid = threadIdx.x;
    for (int t = tid; t < ED * C; t += 256) was[t] = wa[t];
    if (tid < C) bas[tid] = ba[tid];
    __syncthreads();

    const int w  = tid >> 6;
    const int l  = tid & 63;
    const int s  = blockIdx.x * 4 + w;     // 2500*4 == 10000
    const int q  = l >> 4;                 // k-block 0..3
    const int el = l & 15;                 // edge row / output col

    const int e0 = offs[s], e1 = offs[s + 1];
    if (e0 == e1) return;

    const unsigned short* up = UT + (size_t)s * (C * C);
    const short8v B1 = *reinterpret_cast<const short8v*>(up + el * C + q * 8);
    const short8v B2 = *reinterpret_cast<const short8v*>(up + (el + 16) * C + q * 8);
    const float c1 = xb[s * C + el];
    const float c2 = xb[s * C + el + 16];
    const float4v C1 = {c1, c1, c1, c1};
    const float4v C2 = {c2, c2, c2, c2};
    float hb[8];
#pragma unroll
    for (int i = 0; i < 8; ++i) hb[i] = bas[q * 8 + i];

    for (int pb = e0; pb < e1; pb += 16) {
        const int p  = pb + el;
        const int pc = (p < e1) ? p : e0;          // clamp (masked at atomic)
        const float* eap = ea_s + (size_t)pc * EAP;
        const float4v ea0 = *reinterpret_cast<const float4v*>(eap);
        const float4v ea1 = *reinterpret_cast<const float4v*>(eap + 4);
        const float   ea8 = eap[8];

        float h[8];
#pragma unroll
        for (int i = 0; i < 8; ++i) h[i] = hb[i];
#pragma unroll
        for (int j = 0; j < ED; ++j) {
            const float ev = (j == 0) ? ea0.x : (j == 1) ? ea0.y : (j == 2) ? ea0.z
                           : (j == 3) ? ea0.w : (j == 4) ? ea1.x : (j == 5) ? ea1.y
                           : (j == 6) ? ea1.z : (j == 7) ? ea1.w : ea8;
            const float4v w0 = *reinterpret_cast<const float4v*>(&was[j * C + q * 8]);
            const float4v w1 = *reinterpret_cast<const float4v*>(&was[j * C + q * 8 + 4]);
            h[0] += ev * w0.x; h[1] += ev * w0.y; h[2] += ev * w0.z; h[3] += ev * w0.w;
            h[4] += ev * w1.x; h[5] += ev * w1.y; h[6] += ev * w1.z; h[7] += ev * w1.w;
        }
        union { int u[4]; short8v v; } A;
#pragma unroll
        for (int v = 0; v < 4; ++v) {
            const unsigned lo = f2bf(fmaxf(h[2 * v], 0.f));
            const unsigned hi = f2bf(fmaxf(h[2 * v + 1], 0.f));
            A.u[v] = (int)(lo | (hi << 16));
        }
        const float4v d1 = __builtin_amdgcn_mfma_f32_16x16x32_bf16(A.v, B1, C1, 0, 0, 0);
        const float4v d2 = __builtin_amdgcn_mfma_f32_16x16x32_bf16(A.v, B2, C2, 0, 0, 0);
#pragma unroll
        for (int r = 0; r < 4; ++r) {
            const int pe = pb + q * 4 + r;          // D row = (l>>4)*4 + r
            if (pe < e1) {
                const int dst = dst_s[pe];
                atomicAdd(&sumbuf[(size_t)dst * C + el],      d1[r]);
                atomicAdd(&sumbuf[(size_t)dst * C + el + 16], d2[r]);
            }
        }
    }
}

// ---------------------------------------------------------------------------
// node2_score: h2[n,o] = relu(sumbuf2[n,o]/cnt + h1[n,:]@root2[:,o] + bias2[o])
//              scores[n] = sum_o h2[n,o]*sig[o]   (h2 never hits global)
// 1250 blocks x 8 nodes.
// ---------------------------------------------------------------------------
__global__ __launch_bounds__(256) void node2_score(const float* __restrict__ h1,
                                                   const float* __restrict__ sumbuf,
                                                   const int* __restrict__ cnt,
                                                   const float* __restrict__ root,
                                                   const float* __restrict__ bias,
                                                   const float* __restrict__ emb,
                                                   const int* __restrict__ signal,
                                                   float* __restrict__ scores) {
    __shared__ float rs[C * C];
    __shared__ float bs[C];
    __shared__ float sig[C];
    __shared__ float xs[8][C];
    const int tid = threadIdx.x;
    for (int t = tid; t < C * C; t += 256) rs[t] = root[t];
    if (tid < C) {
        bs[tid]  = bias[tid];
        sig[tid] = emb[(size_t)signal[0] * C + tid];
    }
    const int nl = tid >> 5, o = tid & 31;
    const int n  = blockIdx.x * 8 + nl;               // 1250*8 == 10000
    xs[nl][o] = h1[(size_t)n * C + o];
    __syncthreads();
    float acc = bs[o];
#pragma unroll
    for (int i = 0; i < C; ++i) acc += xs[nl][i] * rs[i * C + o];
    const float cn = fmaxf((float)cnt[n], 1.f);
    acc += sumbuf[(size_t)n * C + o] / cn;
    float val = fmaxf(acc, 0.f) * sig[o];
#pragma unroll
    for (int off = 16; off; off >>= 1) val += __shfl_xor(val, off, 32);
    if (o == 0) scores[n] = val;
}

// ---------------------------------------------------------------------------
// reduce_out_kernel: single block; logsumexp then writes the final output.
// ---------------------------------------------------------------------------
__global__ __launch_bounds__(1024) void reduce_out_kernel(const float* __restrict__ scores,
                                                          float* __restrict__ out) {
    __shared__ float sm[16];
    __shared__ float ss[16];
    const int tid = threadIdx.x;
    float m = -INFINITY;
    for (int n = tid; n < NN; n += 1024) m = fmaxf(m, scores[n]);
    for (int off = 32; off; off >>= 1) m = fmaxf(m, __shfl_down(m, off, 64));
    if ((tid & 63) == 0) sm[tid >> 6] = m;
    __syncthreads();
    if (tid == 0) {
        float mm = sm[0];
        for (int w = 1; w < 16; ++w) mm = fmaxf(mm, sm[w]);
        sm[0] = mm;
    }
    __syncthreads();
    const float gmax = sm[0];
    float s = 0.f;
    for (int n = tid; n < NN; n += 1024) s += expf(scores[n] - gmax);
    for (int off = 32; off; off >>= 1) s += __shfl_down(s, off, 64);
    if ((tid & 63) == 0) ss[tid >> 6] = s;
    __syncthreads();
    if (tid == 0) {
        float t = 0.f;
        for (int w = 0; w < 16; ++w) t += ss[w];
        ss[0] = logf(t);
    }
    __syncthreads();
    const float sub = gmax + ss[0];
    for (int n = tid; n < NN; n += 1024) out[n] = scores[n] - sub;
}

// ---------------------------------------------------------------------------
extern "C" void kernel_launch(void* const* d_in, const int* in_sizes, int n_in,
                              void* d_out, int out_size, void* d_ws, size_t ws_size,
                              hipStream_t stream) {
    const int*   signal = (const int*)d_in[0];
    const float* x      = (const float*)d_in[1];
    const int*   ei     = (const int*)d_in[2];
    const float* ea     = (const float*)d_in[3];
    const float* w1a    = (const float*)d_in[4];
    const float* b1a    = (const float*)d_in[5];
    const float* w1b    = (const float*)d_in[6];
    const float* b1b    = (const float*)d_in[7];
    const float* root1  = (const float*)d_in[8];
    const float* bias1  = (const float*)d_in[9];
    const float* w2a    = (const float*)d_in[10];
    const float* b2a    = (const float*)d_in[11];
    const float* w2b    = (const float*)d_in[12];
    const float* b2b    = (const float*)d_in[13];
    const float* root2  = (const float*)d_in[14];
    const float* bias2  = (const float*)d_in[15];
    const float* emb    = (const float*)d_in[16];

    // ---- workspace layout (float words) ----
    float* ws = (float*)d_ws;
    unsigned short* UT = (unsigned short*)ws;         // 5,120,000 words (20.5 MB)
    float* xb      = ws + 5120000;                    // 320,000
    float* h1      = xb + NN * C;                     // 320,000
    float* ea_s    = h1 + NN * C;                     // NE*EAP = 1,920,000
    float* wbT1    = ea_s + (size_t)NE * EAP;         // 32,768
    float* wbT2    = wbT1 + 32768;                    // 32,768
    float* scores  = wbT2 + 32768;                    // 10,000
    // ---- contiguous zero region (zeroed by prep_kernel each call) ----
    float* sumbuf1 = scores + NN;                     // 320,000
    float* sumbuf2 = sumbuf1 + NN * C;                // 320,000
    int*   cnt_src = (int*)(sumbuf2 + NN * C);        // 10,000
    int*   cnt_dst = cnt_src + NN;                    // 10,000
    int*   cursor  = cnt_dst + NN;                    // 10,000
    // ---- end zero region: 670,000 words == 167,500 uint4 ----
    int*   offs    = cursor + NN;                     // 10,016
    int*   dst_s   = offs + NN + 16;                  // 160,000

    const int n16 = 167500;

    // 1: zero + both wb transposes
    prep_kernel<<<ZB + 256, 256, 0, stream>>>((uint4*)sumbuf1, n16, w1b, w2b, wbT1, wbT2);
    // 2-4: CSR by src (reused by both convs)
    hist_kernel<<<(NE + 255) / 256, 256, 0, stream>>>(ei, cnt_src, cnt_dst);
    scan_kernel<<<1, 1024, 0, stream>>>(cnt_src, offs);
    scatter_kernel<<<(NE + 255) / 256, 256, 0, stream>>>(ei, ea, offs, cursor, dst_s, ea_s);
    // 5-6: conv1 (node update folded into 7)
    u_gemm2<<<2500, 256, 0, stream>>>(x, wbT1, b1b, UT, xb);
    edge4_kernel<<<2500, 256, 0, stream>>>(offs, dst_s, ea_s, w1a, b1a, UT, xb, sumbuf1);
    // 7-8: conv2 (h1 computed in-fused; h2 never materialized)
    u_gemm2_fused<<<2500, 256, 0, stream>>>(x, sumbuf1, cnt_dst, root1, bias1,
                                            wbT2, b2b, UT, xb, h1);
    edge4_kernel<<<2500, 256, 0, stream>>>(offs, dst_s, ea_s, w2a, b2a, UT, xb, sumbuf2);
    // 9: node2 + score fused
    node2_score<<<1250, 256, 0, stream>>>(h1, sumbuf2, cnt_dst, root2, bias2,
                                          emb, signal, scores);
    // 10: logsumexp + output
    reduce_out_kernel<<<1, 1024, 0, stream>>>(scores, (float*)d_out);
}